// Round 4
// baseline (359.553 us; speedup 1.0000x reference)
//
#include <hip/hip_runtime.h>

// KacLayer: out[512][4096] = x @ W^T + b  +  Kac2( vec * Kac1( x ) )
//
//  ksched: per 4096-step window (4 steps/thread, 1024 thr), dependency-round
//          election (ping-pong atomicMin). Rounds padded to x128 AND separated
//          by a full identity-pad chunk (cols 4096/4097, outside real range);
//          one pad chunk also ends each slot. Records written position-ordered
//          (coalesced) via a u16 inverse permutation. Bit-exact reorder.
//  kgemm : bf16-MFMA GEMM, out = x@W^T + b.
//  kwalk : 1 wave / 2 rows interleaved as float2 in LDS (b64 DS ops).
//          Because consecutive chunks never conflict (pad-chunk separation),
//          next-chunk gathers are issued BEFORE current-chunk scatters —
//          the in-order per-wave DS pipe (empirically verified in R3) makes
//          this safe, and the LDS latency chain is broken every iteration.

#define DIM    4096
#define ROWS   512
#define NSTEPS 49152
#define WSTEPS 4096
#define NW2    (NSTEPS / WSTEPS)   // 12 windows per walk
#define NSLOT  (2 * NW2)           // 24 slots
#define SLOT   8192                // record capacity per slot
#define MAXR   48
#define CHUNK  128
#define PADI   4096
#define PADJ   4097

typedef short  short8 __attribute__((ext_vector_type(8)));
typedef __bf16 bf16x8 __attribute__((ext_vector_type(8)));
typedef float  f32x4  __attribute__((ext_vector_type(4)));

__device__ inline short f2bf(float f) {
    unsigned u = __builtin_bit_cast(unsigned, f);
    u += 0x7FFFu + ((u >> 16) & 1u);
    return (short)(u >> 16);
}
__device__ inline short8 pack8(float4 a, float4 b) {
    short8 r;
    r[0] = f2bf(a.x); r[1] = f2bf(a.y); r[2] = f2bf(a.z); r[3] = f2bf(a.w);
    r[4] = f2bf(b.x); r[5] = f2bf(b.y); r[6] = f2bf(b.z); r[7] = f2bf(b.w);
    return r;
}
__device__ inline float bitf(unsigned u) { return __builtin_bit_cast(float, u); }

// ---------------------------------------------------------------------------
// 1) schedule kernel: one block per 4096-step window, 4 steps/thread
// ---------------------------------------------------------------------------
__global__ __launch_bounds__(1024) void ksched(
    const int* __restrict__ i1, const int* __restrict__ j1,
    const float* __restrict__ c1, const float* __restrict__ s1,
    const int* __restrict__ i2, const int* __restrict__ j2,
    const float* __restrict__ c2, const float* __restrict__ s2,
    uint4* __restrict__ recs, int* __restrict__ cnts) {

    __shared__ unsigned tblA[DIM], tblB[DIM];
    __shared__ unsigned iq[WSTEPS];
    __shared__ float    csc[WSTEPS], css[WSTEPS];
    __shared__ unsigned short inv[SLOT];
    __shared__ int cnt[MAXR], off[MAXR], idx[MAXR];
    __shared__ int stotal;

    const int b    = blockIdx.x;            // 0..23
    const int walk = b / NW2;
    const int w    = b % NW2;
    const int t    = threadIdx.x;

    const int*   I = walk ? i2 : i1;
    const int*   J = walk ? j2 : j1;
    const float* C = walk ? c2 : c1;
    const float* S = walk ? s2 : s1;

    int li[4], lj[4], myr[4];
#pragma unroll
    for (int q = 0; q < 4; ++q) {
        const int ls = t + q * 1024;
        const int gs = w * WSTEPS + ls;
        li[q] = I[gs]; lj[q] = J[gs];
        iq[ls]  = (unsigned)li[q] | ((unsigned)lj[q] << 16);
        csc[ls] = C[gs]; css[ls] = S[gs];
        myr[q]  = -1;
    }
    if (t < MAXR) { cnt[t] = 0; idx[t] = 0; }
#pragma unroll
    for (int q = 0; q < 4; ++q) { tblA[li[q]] = 0xFFFFFFFFu; tblA[lj[q]] = 0xFFFFFFFFu; }
    __syncthreads();

    // ---- election: winner = min pending (local) step on BOTH its columns --
    unsigned* cur = tblA;
    unsigned* nxt = tblB;
    int npend = 4;
    for (int rr = 0; rr < MAXR; ++rr) {
#pragma unroll
        for (int q = 0; q < 4; ++q)
            if (myr[q] < 0) {
                const unsigned ls = (unsigned)(t + q * 1024);
                atomicMin(&cur[li[q]], ls); atomicMin(&cur[lj[q]], ls);
            }
        __syncthreads();
#pragma unroll
        for (int q = 0; q < 4; ++q)
            if (myr[q] < 0) {
                const unsigned ls = (unsigned)(t + q * 1024);
                if (cur[li[q]] == ls && cur[lj[q]] == ls) { myr[q] = rr; --npend; }
            }
#pragma unroll
        for (int q = 0; q < 4; ++q)
            if (myr[q] < 0) { nxt[li[q]] = 0xFFFFFFFFu; nxt[lj[q]] = 0xFFFFFFFFu; }
        const int np = __syncthreads_count(npend > 0 ? 1 : 0);
        if (np == 0) break;
        unsigned* tmp = cur; cur = nxt; nxt = tmp;
    }
#pragma unroll
    for (int q = 0; q < 4; ++q) {
        if (myr[q] < 0) myr[q] = MAXR - 1;      // statistically unreachable
        atomicAdd(&cnt[myr[q]], 1);
    }
    __syncthreads();

    // ---- offsets: each non-empty round -> ceil128 segment + one pad chunk --
    if (t == 0) {
        int o = 0;
        for (int r = 0; r < MAXR; ++r) {
            if (cnt[r] > 0) {
                off[r] = o;
                o += ((cnt[r] + CHUNK - 1) & ~(CHUNK - 1)) + CHUNK;
            } else off[r] = 0;
        }
        stotal  = (o > SLOT) ? SLOT : o;        // trailing pad chunk included
        cnts[b] = stotal;
    }
    __syncthreads();

    const int total = stotal;
    for (int k = t; k < total; k += 1024) inv[k] = 0xFFFFu;
    __syncthreads();
#pragma unroll
    for (int q = 0; q < 4; ++q) {
        const int p = off[myr[q]] + atomicAdd(&idx[myr[q]], 1);
        if (p < SLOT) inv[p] = (unsigned short)(t + q * 1024);
    }
    __syncthreads();

    // ---- coalesced position-ordered record emission ------------------------
    uint4* slotp = recs + (size_t)b * SLOT;
    const uint4 padrec = { (unsigned)PADI | ((unsigned)PADJ << 16),
                           __builtin_bit_cast(unsigned, 1.0f), 0u, 0u };
    for (int k = t; k < total; k += 1024) {
        const unsigned short s = inv[k];
        uint4 r = padrec;
        if (s != 0xFFFFu) {
            r.x = iq[s];
            r.y = __builtin_bit_cast(unsigned, csc[s]);
            r.z = __builtin_bit_cast(unsigned, css[s]);
        }
        slotp[k] = r;
    }
}

// ---------------------------------------------------------------------------
// 2) bf16 MFMA GEMM: out = x @ W^T + b      (BM=64, BN=128, BK=64, 256 thr)
// ---------------------------------------------------------------------------
#define BM  64
#define BN  128
#define BK  64
#define LDT 72

__global__ __launch_bounds__(256) void kgemm(const float* __restrict__ X, const float* __restrict__ W,
                                             const float* __restrict__ bias, float* __restrict__ out) {
    __shared__ short As[BM * LDT];
    __shared__ short Bs[BN * LDT];
    const int tid  = threadIdx.x;
    const int bn   = (blockIdx.x & 31) * BN;
    const int bm   = (blockIdx.x >> 5) * BM;
    const int lane = tid & 63;
    const int wv   = tid >> 6;
    const int wr   = (wv >> 1) * 32;
    const int wc   = (wv & 1) * 64;
    const int fr   = lane & 15;
    const int ke   = (lane >> 4) * 8;

    f32x4 acc[2][4];
#pragma unroll
    for (int m = 0; m < 2; ++m)
#pragma unroll
        for (int n = 0; n < 4; ++n) acc[m][n] = (f32x4){0.f, 0.f, 0.f, 0.f};

    const int tr = tid >> 2;
    const int tc = (tid & 3) << 4;

    for (int kt = 0; kt < DIM / BK; ++kt) {
        const int k0 = kt * BK;
        float4 ra[4], rb[2][4];
        {
            const float4* ga = (const float4*)(X + (size_t)(bm + tr) * DIM + k0 + tc);
#pragma unroll
            for (int q = 0; q < 4; ++q) ra[q] = ga[q];
#pragma unroll
            for (int h = 0; h < 2; ++h) {
                const float4* gb = (const float4*)(W + (size_t)(bn + h * 64 + tr) * DIM + k0 + tc);
#pragma unroll
                for (int q = 0; q < 4; ++q) rb[h][q] = gb[q];
            }
        }
        __syncthreads();
        *(short8*)&As[tr * LDT + tc]     = pack8(ra[0], ra[1]);
        *(short8*)&As[tr * LDT + tc + 8] = pack8(ra[2], ra[3]);
#pragma unroll
        for (int h = 0; h < 2; ++h) {
            *(short8*)&Bs[(h * 64 + tr) * LDT + tc]     = pack8(rb[h][0], rb[h][1]);
            *(short8*)&Bs[(h * 64 + tr) * LDT + tc + 8] = pack8(rb[h][2], rb[h][3]);
        }
        __syncthreads();
#pragma unroll
        for (int kk = 0; kk < BK; kk += 32) {
            short8 af[2], bf[4];
#pragma unroll
            for (int m = 0; m < 2; ++m)
                af[m] = *(const short8*)&As[(wr + m * 16 + fr) * LDT + kk + ke];
#pragma unroll
            for (int n = 0; n < 4; ++n)
                bf[n] = *(const short8*)&Bs[(wc + n * 16 + fr) * LDT + kk + ke];
#pragma unroll
            for (int m = 0; m < 2; ++m)
#pragma unroll
                for (int n = 0; n < 4; ++n)
                    acc[m][n] = __builtin_amdgcn_mfma_f32_16x16x32_bf16(
                        __builtin_bit_cast(bf16x8, af[m]),
                        __builtin_bit_cast(bf16x8, bf[n]),
                        acc[m][n], 0, 0, 0);
        }
    }
#pragma unroll
    for (int n = 0; n < 4; ++n) {
        const int col = bn + wc + n * 16 + fr;
        const float bv = bias[col];
#pragma unroll
        for (int m = 0; m < 2; ++m) {
            const int rbase = bm + wr + m * 16 + (lane >> 4) * 4;
#pragma unroll
            for (int r = 0; r < 4; ++r)
                out[(size_t)(rbase + r) * DIM + col] = acc[m][n][r] + bv;
        }
    }
}

// ---------------------------------------------------------------------------
// 3) walk kernel: 1 wave / 2 rows (float2-interleaved), gather-ahead pipeline
// ---------------------------------------------------------------------------
__global__ __launch_bounds__(64) void kwalk(const float* __restrict__ X, const float* __restrict__ vec,
                                            const uint4* __restrict__ recs, const int* __restrict__ cnts,
                                            float* __restrict__ out) {
    __shared__ float2 rw[DIM + 2];          // rw[c] = {rowA[c], rowB[c]}; +pad slots
    const int pr   = blockIdx.x;
    const int lane = threadIdx.x;
    const int rA   = pr * 2, rB = pr * 2 + 1;

    {   // interleaved init
        const float4* xa = (const float4*)(X + (size_t)rA * DIM);
        const float4* xb = (const float4*)(X + (size_t)rB * DIM);
        for (int c4 = lane; c4 < DIM / 4; c4 += 64) {
            const float4 a = xa[c4], b = xb[c4];
            rw[c4 * 4 + 0] = make_float2(a.x, b.x);
            rw[c4 * 4 + 1] = make_float2(a.y, b.y);
            rw[c4 * 4 + 2] = make_float2(a.z, b.z);
            rw[c4 * 4 + 3] = make_float2(a.w, b.w);
        }
    }

    const int cn = cnts[(lane < NSLOT) ? lane : 0];   // per-slot totals, via shfl

    for (int walk = 0; walk < 2; ++walk) {
        if (walk == 1) {
            const float4* v4 = (const float4*)vec;
            for (int c4 = lane; c4 < DIM / 4; c4 += 64) {
                const float4 v = v4[c4];
#pragma unroll
                for (int q = 0; q < 4; ++q) {
                    float2 tv = rw[c4 * 4 + q];
                    const float sc = (q == 0) ? v.x : (q == 1) ? v.y : (q == 2) ? v.z : v.w;
                    tv.x *= sc; tv.y *= sc;
                    rw[c4 * 4 + q] = tv;
                }
            }
        }
        const int slot0 = walk * NW2;
        // prologue: records for chunks 0,1 of first slot; gather chunk-0 values
        const uint4* b0 = recs + (size_t)slot0 * SLOT;
        uint4 q0 = b0[lane],       q1 = b0[64 + lane];
        uint4 n0 = b0[128 + lane], n1 = b0[192 + lane];
        int ci0 = q0.x & 0xFFFF, cj0 = q0.x >> 16;
        int ci1 = q1.x & 0xFFFF, cj1 = q1.x >> 16;
        float2 g0 = rw[ci0], g1 = rw[cj0], g2 = rw[ci1], g3 = rw[cj1];

        for (int slot = slot0; slot < slot0 + NW2; ++slot) {
            const int nit = __shfl(cn, slot) / CHUNK;
            const uint4* wb = recs + (size_t)slot * SLOT;
            const uint4* nb = recs + (size_t)((slot + 1 < slot0 + NW2) ? slot + 1 : slot) * SLOT;

            for (int it = 0; it < nit; ++it) {
                // record prefetch for chunk it+2 (static addresses)
                const int idx2 = it + 2;
                const uint4* p2 = (idx2 < nit) ? (wb + (size_t)idx2 * CHUNK)
                                               : (nb + (size_t)(idx2 - nit) * CHUNK);
                const uint4 m0 = p2[lane];
                const uint4 m1 = p2[64 + lane];

                // gather NEXT chunk's values BEFORE this chunk's scatters:
                // consecutive chunks never conflict (same round, or pad chunk).
                const int ni0 = n0.x & 0xFFFF, nj0 = n0.x >> 16;
                const int ni1 = n1.x & 0xFFFF, nj1 = n1.x >> 16;
                const float2 h0 = rw[ni0], h1 = rw[nj0], h2 = rw[ni1], h3 = rw[nj1];

                // rotate current chunk (2 records x 2 rows per lane)
                const float c0 = bitf(q0.y), s0 = bitf(q0.z);
                const float c1 = bitf(q1.y), s1 = bitf(q1.z);
                float2 wi0, wj0, wi1, wj1;
                wi0.x = fmaf(c0, g0.x,  s0 * g1.x);  wi0.y = fmaf(c0, g0.y,  s0 * g1.y);
                wj0.x = fmaf(c0, g1.x, -s0 * g0.x);  wj0.y = fmaf(c0, g1.y, -s0 * g0.y);
                wi1.x = fmaf(c1, g2.x,  s1 * g3.x);  wi1.y = fmaf(c1, g2.y,  s1 * g3.y);
                wj1.x = fmaf(c1, g3.x, -s1 * g2.x);  wj1.y = fmaf(c1, g3.y, -s1 * g2.y);
                rw[ci0] = wi0; rw[cj0] = wj0; rw[ci1] = wi1; rw[cj1] = wj1;

                // rotate pipeline state
                q0 = n0; q1 = n1; n0 = m0; n1 = m1;
                ci0 = ni0; cj0 = nj0; ci1 = ni1; cj1 = nj1;
                g0 = h0; g1 = h1; g2 = h2; g3 = h3;
            }
        }
    }

    // out += walked rows (de-interleave)
    float4* oa = (float4*)(out + (size_t)rA * DIM);
    float4* ob = (float4*)(out + (size_t)rB * DIM);
    for (int c4 = lane; c4 < DIM / 4; c4 += 64) {
        const float2 p0 = rw[c4 * 4 + 0], p1 = rw[c4 * 4 + 1];
        const float2 p2 = rw[c4 * 4 + 2], p3 = rw[c4 * 4 + 3];
        float4 ta = oa[c4], tb = ob[c4];
        ta.x += p0.x; ta.y += p1.x; ta.z += p2.x; ta.w += p3.x;
        tb.x += p0.y; tb.y += p1.y; tb.z += p2.y; tb.w += p3.y;
        oa[c4] = ta; ob[c4] = tb;
    }
}

// ---------------------------------------------------------------------------
extern "C" void kernel_launch(void* const* d_in, const int* in_sizes, int n_in,
                              void* d_out, int out_size, void* d_ws, size_t ws_size,
                              hipStream_t stream) {
    const float* X    = (const float*)d_in[0];
    const float* W    = (const float*)d_in[1];
    const float* bias = (const float*)d_in[2];
    const float* vec  = (const float*)d_in[3];
    const int*   i1   = (const int*)d_in[4];
    const int*   j1   = (const int*)d_in[5];
    const float* c1   = (const float*)d_in[6];
    const float* s1   = (const float*)d_in[7];
    const int*   i2   = (const int*)d_in[8];
    const int*   j2   = (const int*)d_in[9];
    const float* c2   = (const float*)d_in[10];
    const float* s2   = (const float*)d_in[11];
    float* out = (float*)d_out;

    uint4* recs = (uint4*)d_ws;                        // 24*8192*16B = 3 MiB
    int*   cnts = (int*)((char*)d_ws + (size_t)NSLOT * SLOT * 16);

    hipLaunchKernelGGL(ksched, dim3(NSLOT), dim3(1024), 0, stream,
                       i1, j1, c1, s1, i2, j2, c2, s2, recs, cnts);
    hipLaunchKernelGGL(kgemm,  dim3(256), dim3(256), 0, stream, X, W, bias, out);
    hipLaunchKernelGGL(kwalk,  dim3(ROWS / 2), dim3(64), 0, stream, X, vec, recs, cnts, out);
}

// Round 5
// 343.052 us; speedup vs baseline: 1.0481x; 1.0481x over previous
//
#include <hip/hip_runtime.h>

// KacLayer: out[512][4096] = x @ W^T + b  +  Kac2( vec * Kac1( x ) )
//
//  ksched: per 8192-step window (16 steps/thread, 512 thr), dependency-round
//          election with round-stamped atomicMin keys (program order preserved
//          on shared columns). Each non-empty round emitted as ceil128 segment
//          + TWO identity-pad chunks (cols 4096/4097) -> any 3 consecutive
//          chunks are column-disjoint. Bit-exact reorder of commuting Givens.
//  kgemm : bf16-MFMA GEMM with register double-buffer, out = x@W^T + b.
//  kwalk : 1 wave / 2 rows (float2-interleaved LDS). 3-stage software
//          pipeline: records loaded 4 chunks ahead, decoded+gathered 2 chunks
//          ahead, rotated+scattered at stage 0. In-order per-wave DS pipe +
//          2-pad-chunk separation make gather-before-scatter safe.

#define DIM    4096
#define ROWS   512
#define NSTEPS 49152
#define WSTEPS 8192
#define NW2    (NSTEPS / WSTEPS)   // 6 windows per walk
#define NSLOT  (2 * NW2)           // 12 slots
#define SLOT   20480               // record capacity per slot (rounds<=38)
#define MAXR   64
#define CHUNK  128
#define PADI   4096
#define PADJ   4097
#define KT     512                 // ksched threads
#define SPT    (WSTEPS / KT)       // 16 steps per thread

typedef short  short8 __attribute__((ext_vector_type(8)));
typedef __bf16 bf16x8 __attribute__((ext_vector_type(8)));
typedef float  f32x4  __attribute__((ext_vector_type(4)));

__device__ inline short f2bf(float f) {
    unsigned u = __builtin_bit_cast(unsigned, f);
    u += 0x7FFFu + ((u >> 16) & 1u);
    return (short)(u >> 16);
}
__device__ inline short8 pack8(float4 a, float4 b) {
    short8 r;
    r[0] = f2bf(a.x); r[1] = f2bf(a.y); r[2] = f2bf(a.z); r[3] = f2bf(a.w);
    r[4] = f2bf(b.x); r[5] = f2bf(b.y); r[6] = f2bf(b.z); r[7] = f2bf(b.w);
    return r;
}
__device__ inline float bitf(unsigned u) { return __builtin_bit_cast(float, u); }

// ---------------------------------------------------------------------------
// 1) schedule kernel: one block per 8192-step window
// ---------------------------------------------------------------------------
__global__ __launch_bounds__(KT) void ksched(
    const int* __restrict__ i1, const int* __restrict__ j1,
    const float* __restrict__ c1, const float* __restrict__ s1,
    const int* __restrict__ i2, const int* __restrict__ j2,
    const float* __restrict__ c2, const float* __restrict__ s2,
    uint4* __restrict__ recs, int* __restrict__ cnts) {

    __shared__ unsigned tbl[DIM];
    __shared__ unsigned short inv[SLOT];
    __shared__ int cnt[MAXR], off[MAXR], idx[MAXR];
    __shared__ int done, stotal;

    const int b    = blockIdx.x;            // 0..11
    const int walk = b / NW2;
    const int w    = b % NW2;
    const int t    = threadIdx.x;
    const int gb   = w * WSTEPS;

    const int*   I = walk ? i2 : i1;
    const int*   J = walk ? j2 : j1;
    const float* C = walk ? c2 : c1;
    const float* S = walk ? s2 : s1;

    unsigned short li[SPT], lj[SPT];
    signed char    myr[SPT];
#pragma unroll
    for (int q = 0; q < SPT; ++q) {
        const int s = q * KT + t;
        li[q] = (unsigned short)I[gb + s];
        lj[q] = (unsigned short)J[gb + s];
        myr[q] = -1;
    }
    for (int k = t; k < DIM; k += KT) tbl[k] = 0xFFFFFFFFu;
    if (t < MAXR) { cnt[t] = 0; idx[t] = 0; }
    if (t == 0)   done = 0;
    __syncthreads();

    // election: key = ((MAXR-1-rr)<<13)|step -> later rounds auto-override
    // stale entries (smaller key). Winner = min step on BOTH its columns.
    unsigned pmask = (SPT < 32) ? ((1u << SPT) - 1u) : 0xFFFFFFFFu;
    for (int rr = 0; rr < MAXR; ++rr) {
        const unsigned rk = (unsigned)(MAXR - 1 - rr) << 13;
#pragma unroll
        for (int q = 0; q < SPT; ++q)
            if (pmask & (1u << q)) {
                const unsigned key = rk | (unsigned)(q * KT + t);
                atomicMin(&tbl[li[q]], key);
                atomicMin(&tbl[lj[q]], key);
            }
        __syncthreads();
        int wins = 0;
#pragma unroll
        for (int q = 0; q < SPT; ++q)
            if (pmask & (1u << q)) {
                const unsigned key = rk | (unsigned)(q * KT + t);
                if (tbl[li[q]] == key && tbl[lj[q]] == key) {
                    myr[q] = (signed char)rr; pmask &= ~(1u << q); ++wins;
                }
            }
        if (wins) atomicAdd(&done, wins);
        __syncthreads();
        if (done == WSTEPS) break;
    }
#pragma unroll
    for (int q = 0; q < SPT; ++q) {
        if (myr[q] < 0) myr[q] = MAXR - 1;      // statistically unreachable
        atomicAdd(&cnt[(int)myr[q]], 1);
    }
    __syncthreads();

    // offsets: per non-empty round: ceil128(cnt) + 2 pad chunks
    if (t == 0) {
        int o = 0;
        for (int r = 0; r < MAXR; ++r)
            if (cnt[r] > 0) { off[r] = o; o += ((cnt[r] + 127) & ~127) + 2 * CHUNK; }
        stotal  = (o > SLOT) ? SLOT : o;
        cnts[b] = stotal;
    }
    __syncthreads();

    const int tot = stotal;
    for (int k = t; k < tot; k += KT) inv[k] = 0xFFFFu;
    __syncthreads();
#pragma unroll
    for (int q = 0; q < SPT; ++q) {
        const int p = off[(int)myr[q]] + atomicAdd(&idx[(int)myr[q]], 1);
        if (p < SLOT) inv[p] = (unsigned short)(q * KT + t);
    }
    __syncthreads();

    // coalesced position-ordered emission
    uint4* slotp = recs + (size_t)b * SLOT;
    for (int k = t; k < tot; k += KT) {
        const unsigned s = inv[k];
        uint4 r = { (unsigned)PADI | ((unsigned)PADJ << 16), 0x3F800000u, 0u, 0u };
        if (s != 0xFFFFu) {
            const int g = gb + (int)s;
            r.x = (unsigned)I[g] | ((unsigned)J[g] << 16);
            r.y = __builtin_bit_cast(unsigned, C[g]);
            r.z = __builtin_bit_cast(unsigned, S[g]);
        }
        slotp[k] = r;
    }
}

// ---------------------------------------------------------------------------
// 2) bf16 MFMA GEMM: out = x @ W^T + b   (BM=64, BN=128, BK=64, reg-dbuf)
// ---------------------------------------------------------------------------
#define BM  64
#define BN  128
#define BK  64
#define LDT 72

#define LOADTILE(KTI, A, B)                                                      \
    {                                                                            \
        const int k0_ = (KTI) * BK;                                              \
        const float4* ga_ = (const float4*)(X + (size_t)(bm + tr) * DIM + k0_ + tc); \
        _Pragma("unroll") for (int q = 0; q < 4; ++q) A[q] = ga_[q];             \
        _Pragma("unroll") for (int h = 0; h < 2; ++h) {                          \
            const float4* gb_ = (const float4*)(W + (size_t)(bn + h * 64 + tr) * DIM + k0_ + tc); \
            _Pragma("unroll") for (int q = 0; q < 4; ++q) B[h][q] = gb_[q];      \
        }                                                                        \
    }

__global__ __launch_bounds__(256) void kgemm(const float* __restrict__ X, const float* __restrict__ W,
                                             const float* __restrict__ bias, float* __restrict__ out) {
    __shared__ short As[BM * LDT];
    __shared__ short Bs[BN * LDT];
    const int tid  = threadIdx.x;
    const int bn   = (blockIdx.x & 31) * BN;
    const int bm   = (blockIdx.x >> 5) * BM;
    const int lane = tid & 63;
    const int wv   = tid >> 6;
    const int wr   = (wv >> 1) * 32;
    const int wc   = (wv & 1) * 64;
    const int fr   = lane & 15;
    const int ke   = (lane >> 4) * 8;

    f32x4 acc[2][4];
#pragma unroll
    for (int m = 0; m < 2; ++m)
#pragma unroll
        for (int n = 0; n < 4; ++n) acc[m][n] = (f32x4){0.f, 0.f, 0.f, 0.f};

    const int tr = tid >> 2;
    const int tc = (tid & 3) << 4;

    float4 ra[4], rb[2][4];
    LOADTILE(0, ra, rb);

#pragma unroll 2
    for (int kt = 0; kt < DIM / BK; ++kt) {
        __syncthreads();   // previous tile's LDS reads done
        *(short8*)&As[tr * LDT + tc]     = pack8(ra[0], ra[1]);
        *(short8*)&As[tr * LDT + tc + 8] = pack8(ra[2], ra[3]);
#pragma unroll
        for (int h = 0; h < 2; ++h) {
            *(short8*)&Bs[(h * 64 + tr) * LDT + tc]     = pack8(rb[h][0], rb[h][1]);
            *(short8*)&Bs[(h * 64 + tr) * LDT + tc + 8] = pack8(rb[h][2], rb[h][3]);
        }
        __syncthreads();
        float4 na[4], nb[2][4];
        if (kt + 1 < DIM / BK) LOADTILE(kt + 1, na, nb);   // issue before MFMA
#pragma unroll
        for (int kk = 0; kk < BK; kk += 32) {
            short8 af[2], bf[4];
#pragma unroll
            for (int m = 0; m < 2; ++m)
                af[m] = *(const short8*)&As[(wr + m * 16 + fr) * LDT + kk + ke];
#pragma unroll
            for (int n = 0; n < 4; ++n)
                bf[n] = *(const short8*)&Bs[(wc + n * 16 + fr) * LDT + kk + ke];
#pragma unroll
            for (int m = 0; m < 2; ++m)
#pragma unroll
                for (int n = 0; n < 4; ++n)
                    acc[m][n] = __builtin_amdgcn_mfma_f32_16x16x32_bf16(
                        __builtin_bit_cast(bf16x8, af[m]),
                        __builtin_bit_cast(bf16x8, bf[n]),
                        acc[m][n], 0, 0, 0);
        }
#pragma unroll
        for (int q = 0; q < 4; ++q) ra[q] = na[q];
#pragma unroll
        for (int h = 0; h < 2; ++h)
#pragma unroll
            for (int q = 0; q < 4; ++q) rb[h][q] = nb[h][q];
    }
#pragma unroll
    for (int n = 0; n < 4; ++n) {
        const int col = bn + wc + n * 16 + fr;
        const float bv = bias[col];
#pragma unroll
        for (int m = 0; m < 2; ++m) {
            const int rbase = bm + wr + m * 16 + (lane >> 4) * 4;
#pragma unroll
            for (int r = 0; r < 4; ++r)
                out[(size_t)(rbase + r) * DIM + col] = acc[m][n][r] + bv;
        }
    }
}

// ---------------------------------------------------------------------------
// 3) walk kernel: 1 wave / 2 rows, 3-stage pipeline (load+4 / gather+2 / do)
// ---------------------------------------------------------------------------
__global__ __launch_bounds__(64) void kwalk(const float* __restrict__ X, const float* __restrict__ vec,
                                            const uint4* __restrict__ recs, const int* __restrict__ cnts,
                                            float* __restrict__ out) {
    __shared__ float2 rw[DIM + 2];          // rw[c] = {rowA[c], rowB[c]}
    const int pr   = blockIdx.x;
    const int lane = threadIdx.x;
    const int rA   = pr * 2, rB = pr * 2 + 1;

    {
        const float4* xa = (const float4*)(X + (size_t)rA * DIM);
        const float4* xb = (const float4*)(X + (size_t)rB * DIM);
        for (int c4 = lane; c4 < DIM / 4; c4 += 64) {
            const float4 a = xa[c4], b = xb[c4];
            rw[c4 * 4 + 0] = make_float2(a.x, b.x);
            rw[c4 * 4 + 1] = make_float2(a.y, b.y);
            rw[c4 * 4 + 2] = make_float2(a.z, b.z);
            rw[c4 * 4 + 3] = make_float2(a.w, b.w);
        }
        if (lane < 2) rw[DIM + lane] = make_float2(0.f, 0.f);
    }

    const int cnreg = cnts[lane < NSLOT ? lane : 0];

    for (int slot = 0; slot < NSLOT; ++slot) {
        if (slot == NW2) {      // between walks: yp = vec * yp
            const float4* v4 = (const float4*)vec;
            for (int c4 = lane; c4 < DIM / 4; c4 += 64) {
                const float4 v = v4[c4];
#pragma unroll
                for (int q = 0; q < 4; ++q) {
                    float2 tv = rw[c4 * 4 + q];
                    const float sc = (q == 0) ? v.x : (q == 1) ? v.y : (q == 2) ? v.z : v.w;
                    tv.x *= sc; tv.y *= sc;
                    rw[c4 * 4 + q] = tv;
                }
            }
        }
        const int nit = __shfl(cnreg, slot) >> 7;     // chunks this slot (>=64)
        const uint4* base = recs + (size_t)slot * SLOT;

        // ---- prologue: record ring holds chunks k+2,k+3; stages 0,1 filled
        uint4 rd0A = base[2 * 128 + lane], rd0B = base[2 * 128 + 64 + lane];
        uint4 rd1A = base[3 * 128 + lane], rd1B = base[3 * 128 + 64 + lane];
        uint4 c0A  = base[lane],           c0B  = base[64 + lane];
        uint4 c1A  = base[128 + lane],     c1B  = base[192 + lane];

        int   i0a = c0A.x & 0xFFFF, j0a = (int)(c0A.x >> 16);
        int   i0b = c0B.x & 0xFFFF, j0b = (int)(c0B.x >> 16);
        float cc0a = bitf(c0A.y), ss0a = bitf(c0A.z);
        float cc0b = bitf(c0B.y), ss0b = bitf(c0B.z);
        float2 g0ai = rw[i0a], g0aj = rw[j0a], g0bi = rw[i0b], g0bj = rw[j0b];

        int   i1a = c1A.x & 0xFFFF, j1a = (int)(c1A.x >> 16);
        int   i1b = c1B.x & 0xFFFF, j1b = (int)(c1B.x >> 16);
        float cc1a = bitf(c1A.y), ss1a = bitf(c1A.z);
        float cc1b = bitf(c1B.y), ss1b = bitf(c1B.z);
        float2 g1ai = rw[i1a], g1aj = rw[j1a], g1bi = rw[i1b], g1bj = rw[j1b];

#pragma unroll 4
        for (int k = 0; k < nit; ++k) {
            // stage L: load records for chunk k+4 (clamped -> pad chunks, safe)
            const int kc = (k + 4 < nit) ? (k + 4) : (nit - 1);
            const uint4 mA = base[(size_t)kc * 128 + lane];
            const uint4 mB = base[(size_t)kc * 128 + 64 + lane];

            // stage G: decode + gather chunk k+2 (before stage-0 scatters;
            // safe: any 3 consecutive chunks are column-disjoint by padding)
            const int   i2a = rd0A.x & 0xFFFF, j2a = (int)(rd0A.x >> 16);
            const int   i2b = rd0B.x & 0xFFFF, j2b = (int)(rd0B.x >> 16);
            const float cc2a = bitf(rd0A.y), ss2a = bitf(rd0A.z);
            const float cc2b = bitf(rd0B.y), ss2b = bitf(rd0B.z);
            const float2 g2ai = rw[i2a], g2aj = rw[j2a];
            const float2 g2bi = rw[i2b], g2bj = rw[j2b];

            // stage C: rotate + scatter chunk k
            float2 wia, wja, wib, wjb;
            wia.x = fmaf(cc0a, g0ai.x,  ss0a * g0aj.x);
            wia.y = fmaf(cc0a, g0ai.y,  ss0a * g0aj.y);
            wja.x = fmaf(cc0a, g0aj.x, -ss0a * g0ai.x);
            wja.y = fmaf(cc0a, g0aj.y, -ss0a * g0ai.y);
            wib.x = fmaf(cc0b, g0bi.x,  ss0b * g0bj.x);
            wib.y = fmaf(cc0b, g0bi.y,  ss0b * g0bj.y);
            wjb.x = fmaf(cc0b, g0bj.x, -ss0b * g0bi.x);
            wjb.y = fmaf(cc0b, g0bj.y, -ss0b * g0bi.y);
            rw[i0a] = wia; rw[j0a] = wja; rw[i0b] = wib; rw[j0b] = wjb;

            // rotate pipeline (copies removed by unroll renaming)
            i0a = i1a; j0a = j1a; cc0a = cc1a; ss0a = ss1a; g0ai = g1ai; g0aj = g1aj;
            i0b = i1b; j0b = j1b; cc0b = cc1b; ss0b = ss1b; g0bi = g1bi; g0bj = g1bj;
            i1a = i2a; j1a = j2a; cc1a = cc2a; ss1a = ss2a; g1ai = g2ai; g1aj = g2aj;
            i1b = i2b; j1b = j2b; cc1b = cc2b; ss1b = ss2b; g1bi = g2bi; g1bj = g2bj;
            rd0A = rd1A; rd0B = rd1B; rd1A = mA; rd1B = mB;
        }
    }

    float4* oa = (float4*)(out + (size_t)rA * DIM);
    float4* ob = (float4*)(out + (size_t)rB * DIM);
    for (int c4 = lane; c4 < DIM / 4; c4 += 64) {
        const float2 p0 = rw[c4 * 4 + 0], p1 = rw[c4 * 4 + 1];
        const float2 p2 = rw[c4 * 4 + 2], p3 = rw[c4 * 4 + 3];
        float4 ta = oa[c4], tb = ob[c4];
        ta.x += p0.x; ta.y += p1.x; ta.z += p2.x; ta.w += p3.x;
        tb.x += p0.y; tb.y += p1.y; tb.z += p2.y; tb.w += p3.y;
        oa[c4] = ta; ob[c4] = tb;
    }
}

// ---------------------------------------------------------------------------
extern "C" void kernel_launch(void* const* d_in, const int* in_sizes, int n_in,
                              void* d_out, int out_size, void* d_ws, size_t ws_size,
                              hipStream_t stream) {
    const float* X    = (const float*)d_in[0];
    const float* W    = (const float*)d_in[1];
    const float* bias = (const float*)d_in[2];
    const float* vec  = (const float*)d_in[3];
    const int*   i1   = (const int*)d_in[4];
    const int*   j1   = (const int*)d_in[5];
    const float* c1   = (const float*)d_in[6];
    const float* s1   = (const float*)d_in[7];
    const int*   i2   = (const int*)d_in[8];
    const int*   j2   = (const int*)d_in[9];
    const float* c2   = (const float*)d_in[10];
    const float* s2   = (const float*)d_in[11];
    float* out = (float*)d_out;

    uint4* recs = (uint4*)d_ws;                        // 12*20480*16B = 3.93 MiB
    int*   cnts = (int*)((char*)d_ws + (size_t)NSLOT * SLOT * 16);

    hipLaunchKernelGGL(ksched, dim3(NSLOT), dim3(KT), 0, stream,
                       i1, j1, c1, s1, i2, j2, c2, s2, recs, cnts);
    hipLaunchKernelGGL(kgemm,  dim3(256), dim3(256), 0, stream, X, W, bias, out);
    hipLaunchKernelGGL(kwalk,  dim3(ROWS / 2), dim3(64), 0, stream, X, vec, recs, cnts, out);
}